// Round 9
// baseline (605.495 us; speedup 1.0000x reference)
//
#include <hip/hip_runtime.h>
#include <hip/hip_bf16.h>
#include <math.h>

// Problem constants
#define N_E      16384
#define E_DIM    64
#define GROUPS   4
#define N_E_G    4096
#define NQ       16384     // B*H*W query vectors

// Output layout (element offsets into d_out, float32)
#define OFF_QUANT   0L
#define OFF_VQLOSS  4194304L
#define OFF_PERP    4194316L
#define OFF_MINENC  4194317L
#define OFF_IDX     71303181L
// zero region [OFF_VQLOSS, OFF_IDX): 67,108,877 floats; aligned start.
// 512 slices x 32768 float4 cover 67,108,864; 13-float tail handled by slice 0.

// Workspace layout (element offsets into d_ws as float*/int*)
#define WS_EN     0L          // normalized emb fp32 [4][4096][64]
#define WS_EN2    1048576L    // |e|^2 per code [16384]
#define WS_ENHI   1064960L    // bf16(en) ushort [4][4096][64] -> 524288 floats
#define WS_CAND   1589248L    // ushort [512 slices][128][CAP] -> 2,097,152 floats
#define WS_CNT    3686400L    // int [512][128]
#define WS_HIST   3751936L    // int[4096]
#define WS_IDX3   3756032L    // int[16384]

typedef float  float4v  __attribute__((ext_vector_type(4)));
typedef short  short8   __attribute__((ext_vector_type(8)));

static __device__ __forceinline__ ushort f2bf(float x) {
    union { __hip_bfloat16 h; ushort u; } cv; cv.h = __float2bfloat16(x);
    return cv.u;
}

// ---------------------------------------------------------------------------
// K0: embedding normalization (1024 blocks, 4 codes/wave) + hist zeroing
// (blocks 0..15). Stream order guarantees completion before K1a starts.
__global__ void norm_emb_kernel(const float* __restrict__ emb,
                                float* __restrict__ en, float* __restrict__ en2,
                                ushort* __restrict__ ehi,
                                int* __restrict__ hist) {
    const int t    = threadIdx.x;
    const int lane = t & 63;
    const int wv   = t >> 6;

    if (blockIdx.x < 16) hist[blockIdx.x * 256 + t] = 0;

    #pragma unroll
    for (int it = 0; it < 4; ++it) {
        int code = blockIdx.x * 16 + wv * 4 + it;
        float x = emb[code * 64 + lane];
        float ss = x * x;
        #pragma unroll
        for (int off = 32; off; off >>= 1) ss += __shfl_xor(ss, off, 64);
        float v = x / fmaxf(sqrtf(ss), 1e-12f);
        en[code * 64 + lane]  = v;
        ehi[code * 64 + lane] = f2bf(v);
        float s2 = v * v;
        #pragma unroll
        for (int off = 32; off; off >>= 1) s2 += __shfl_xor(s2, off, 64);
        if (lane == 0) en2[code] = s2;
    }
}

// ---------------------------------------------------------------------------
// R9 ATTRIBUTION SPLIT (ablation round per m164/m177 discipline): five
// structural theories about vq_cand's ~20x stall were each falsified by
// measurement (R3 TLP, R5 occupancy, R6 store-cadence, R7 shfl-latency,
// R8 wave-specialized fill). Split cand-gen and rescore into separate
// dispatches so rocprof attributes the time exactly. Both kernels drop the
// zn LDS buffer (fragments / za built straight from tile+rden, bit-identical
// IEEE ops) -> LDS ~34 KB -> 4 blocks/CU (free 2x-occupancy datapoint at
// 256-thread granularity vs R5's 512-thread test).
// Compute chain identical to the R2 champion: wave-wide shfl capture
// threshold, CAP 64, in-loop NT zero-fill after prefetch loads, serial
// exact fp32 rescore, NT quant writes.
// TAU >= 2*E, E = worst-case |dot - bf16hi-dot| <= 2*2^-8*(1+eps) = 7.83e-3.
#define CAP  64
#define TAU  0.017f

// K1a: z-norm + bf16-hi MFMA K-loop + zero-fill + candidate dump.
__global__ __launch_bounds__(256, 4)
void cand_gen_kernel(const float* __restrict__ z,
                     const ushort* __restrict__ ehi,
                     float* __restrict__ out,
                     ushort* __restrict__ candw, int* __restrict__ cntw) {
    __shared__ float rden[128];
    __shared__ int   cnt[128];
    __shared__ union {                 // tile dead before cand is born
        float  tile[64 * 129];         // 33.0 KB staging (transpose)
        ushort cand[128 * CAP];        // 16 KB
    } sh;                              // ~34 KB total -> 4 blocks/CU

    const int g  = blockIdx.y;
    const int q0 = blockIdx.x * 128;
    const int t  = threadIdx.x;
    const int wave = t >> 6, lane = t & 63;
    const int l15 = lane & 15, quad = lane >> 4;
    const int qhalf = wave & 1, chalf = wave >> 1;

    const int sliceId = blockIdx.y * 128 + blockIdx.x;   // 0..511
    float4v* fill4 = (float4v*)(out + OFF_VQLOSS) + (size_t)sliceId * 32768;

    // First codebook A-tile prefetch; completes while z-normalization runs.
    const ushort* abase = ehi + (size_t)g * N_E_G * 64
                        + (size_t)(chalf * 64 + l15) * 64 + quad * 8;
    short8 afA[4][2], afB[4][2];
    #pragma unroll
    for (int cs = 0; cs < 4; ++cs)
        #pragma unroll
        for (int ks = 0; ks < 2; ++ks)
            afA[cs][ks] = *(const short8*)(abase + (size_t)(cs * 16) * 64 + ks * 32);

    if (t < 128) cnt[t] = 0;

    // ---- stage z tile + row norms (identical math to champion)
    {
        const int b = q0 >> 10, hw0 = q0 & 1023;
        const float* src = z + (size_t)b * 262144 + (size_t)g * 65536 + hw0;
        for (int i = t; i < 8192; i += 256) {
            int d = i >> 7, nq = i & 127;
            sh.tile[d * 129 + nq] = src[(size_t)d * 1024 + nq];
        }
        __syncthreads();
        if (t < 128) {
            float ss = 0.f;
            for (int d = 0; d < 64; ++d) {
                float x = sh.tile[d * 129 + t];
                ss = fmaf(x, x, ss);
            }
            rden[t] = fmaxf(sqrtf(ss), 1e-12f);
        }
        __syncthreads();
    }

    // B-frags built straight from tile+rden (same IEEE divide-then-f2bf
    // chain as champion's zn path; zn buffer eliminated).
    short8 bfrag[4][2];
    #pragma unroll
    for (int uu = 0; uu < 4; ++uu) {
        int ql = qhalf * 64 + uu * 16 + l15;
        float rr = rden[ql];
        #pragma unroll
        for (int ks = 0; ks < 2; ++ks) {
            short8 f;
            #pragma unroll
            for (int j = 0; j < 8; ++j) {
                int col = ks * 32 + quad * 8 + j;
                f[j] = (short)f2bf(sh.tile[col * 129 + ql] / rr);
            }
            bfrag[uu][ks] = f;
        }
    }
    __syncthreads();   // tile reads done; cand may alias tile from here

    float Mrun[4];
    #pragma unroll
    for (int u = 0; u < 4; ++u) Mrun[u] = -3.4e38f;

    auto do_tile = [&](short8 (&A)[4][2], short8 (&P)[4][2], int tile) {
        if (tile + 1 < 32) {
            const ushort* p = abase + (size_t)((tile + 1) * 128) * 64;
            #pragma unroll
            for (int cs = 0; cs < 4; ++cs)
                #pragma unroll
                for (int ks = 0; ks < 2; ++ks)
                    P[cs][ks] = *(const short8*)(p + (size_t)(cs * 16) * 64 + ks * 32);
        }
        // zero-fill slice: 4 nt float4 stores per tile, after prefetch loads
        {
            const float4v z4 = {0.f, 0.f, 0.f, 0.f};
            #pragma unroll
            for (int r = 0; r < 4; ++r)
                __builtin_nontemporal_store(
                    z4, &fill4[(size_t)(tile * 4 + r) * 256 + t]);
        }
        float4v acc[4][4];
        #pragma unroll
        for (int cs = 0; cs < 4; ++cs)
            #pragma unroll
            for (int u = 0; u < 4; ++u) {
                float4v zz = {0.f, 0.f, 0.f, 0.f};
                float4v tmp = __builtin_amdgcn_mfma_f32_16x16x32_bf16(
                                  A[cs][0], bfrag[u][0], zz, 0, 0, 0);
                acc[cs][u] = __builtin_amdgcn_mfma_f32_16x16x32_bf16(
                                  A[cs][1], bfrag[u][1], tmp, 0, 0, 0);
            }
        const int j0 = tile * 128;
        #pragma unroll
        for (int u = 0; u < 4; ++u) {
            float m0 = fmaxf(fmaxf(acc[0][u][0], acc[0][u][1]),
                             fmaxf(acc[0][u][2], acc[0][u][3]));
            float m1 = fmaxf(fmaxf(acc[1][u][0], acc[1][u][1]),
                             fmaxf(acc[1][u][2], acc[1][u][3]));
            float m2 = fmaxf(fmaxf(acc[2][u][0], acc[2][u][1]),
                             fmaxf(acc[2][u][2], acc[2][u][3]));
            float m3 = fmaxf(fmaxf(acc[3][u][0], acc[3][u][1]),
                             fmaxf(acc[3][u][2], acc[3][u][3]));
            float m  = fmaxf(fmaxf(m0, m1), fmaxf(m2, m3));
            float mh = fmaxf(m,  __shfl_xor(m,  16, 64));
            float mw = fmaxf(mh, __shfl_xor(mh, 32, 64));
            Mrun[u] = fmaxf(Mrun[u], mw);
            float thr = Mrun[u] - TAU;
            if (m >= thr) {                    // rare (wave-wide filter)
                int ql = qhalf * 64 + u * 16 + l15;
                #pragma unroll
                for (int cs = 0; cs < 4; ++cs)
                    #pragma unroll
                    for (int r = 0; r < 4; ++r)
                        if (acc[cs][u][r] >= thr) {
                            int cidx = j0 + chalf * 64 + cs * 16 + quad * 4 + r;
                            int slot = atomicAdd(&cnt[ql], 1);
                            if (slot < CAP) sh.cand[ql * CAP + slot] = (ushort)cidx;
                        }
            }
        }
    };

    for (int tt = 0; tt < 32; tt += 2) {
        do_tile(afA, afB, tt);
        do_tile(afB, afA, tt + 1);
    }

    // 13-float tail of the zero region (unaligned remainder)
    if (sliceId == 0 && t < 13) out[OFF_VQLOSS + 67108864L + t] = 0.f;
    __syncthreads();

    // dump candidates (coalesced 4B chunks) + clamped counts
    {
        const uint* s  = (const uint*)sh.cand;
        uint* d2 = (uint*)(candw + (size_t)sliceId * 128 * CAP);
        for (int i = t; i < 128 * CAP / 2; i += 256) d2[i] = s[i];
    }
    if (t < 128) {
        int n = cnt[t];
        cntw[sliceId * 128 + t] = n > CAP ? CAP : n;
    }
}

// ---------------------------------------------------------------------------
// K1b: re-stage z, exact fp32 rescore of dumped candidates, idx/hist/quant.
__global__ __launch_bounds__(256, 4)
void rescore_kernel(const float* __restrict__ z,
                    const float* __restrict__ en,
                    const float* __restrict__ en2,
                    const ushort* __restrict__ candw,
                    const int* __restrict__ cntw,
                    float* __restrict__ out,
                    int* __restrict__ hist, int* __restrict__ idx3) {
    __shared__ float tile[64 * 129];   // 33.0 KB
    __shared__ float rden[128];
    __shared__ int   bks[128];

    const int g  = blockIdx.y;
    const int q0 = blockIdx.x * 128;
    const int t  = threadIdx.x;
    const int sliceId = blockIdx.y * 128 + blockIdx.x;

    {
        const int b = q0 >> 10, hw0 = q0 & 1023;
        const float* src = z + (size_t)b * 262144 + (size_t)g * 65536 + hw0;
        for (int i = t; i < 8192; i += 256) {
            int d = i >> 7, nq = i & 127;
            tile[d * 129 + nq] = src[(size_t)d * 1024 + nq];
        }
        __syncthreads();
        if (t < 128) {
            float ss = 0.f;
            for (int d = 0; d < 64; ++d) {
                float x = tile[d * 129 + t];
                ss = fmaf(x, x, ss);
            }
            rden[t] = fmaxf(sqrtf(ss), 1e-12f);
        }
        __syncthreads();
    }

    // exact fp32 rescore (first-wins == min idx); za from tile+rden
    // (identical IEEE divide chain as champion's zn path)
    if (t < 128) {
        float rr = rden[t];
        float za[64];
        #pragma unroll
        for (int k = 0; k < 64; ++k) za[k] = tile[k * 129 + t] / rr;
        int nc = cntw[sliceId * 128 + t];
        const ushort* cr = candw + (size_t)sliceId * 128 * CAP + t * CAP;
        float best = -3.4e38f; int bk = 0x7fffffff;
        for (int s = 0; s < nc; ++s) {
            int c = cr[s];
            const float* ev = en + ((size_t)g * N_E_G + c) * 64;
            float a = 0.f;
            #pragma unroll
            for (int k = 0; k < 64; ++k) a = fmaf(za[k], ev[k], a);
            float d = 2.f * a - en2[g * N_E_G + c];
            if (d > best || (d == best && c < bk)) { best = d; bk = c; }
        }
        if (bk == 0x7fffffff) bk = 0;
        bks[t] = bk;
        out[OFF_IDX + (size_t)(q0 + t) * 4 + g] = (float)bk;
        if (g == 3) {
            idx3[q0 + t] = bk;
            atomicAdd(&hist[bk], 1);
        }
    }
    __syncthreads();

    // quant write, coalesced along hw, non-temporal (streaming output)
    for (int i = t; i < 128 * 64; i += 256) {
        int d = i >> 7, m = i & 127;
        int n = q0 + m, b = n >> 10, hw = n & 1023;
        float v = en[((size_t)g * N_E_G + bks[m]) * 64 + d];
        __builtin_nontemporal_store(
            v, &out[OFF_QUANT + (size_t)b * 262144 + (size_t)(g * 64 + d) * 1024 + hw]);
    }
}

// ---------------------------------------------------------------------------
// K2: scatter ones (64 blocks, parallel) + perplexity (block 64).
// Stream-ordered after rescore: zero-fill complete, hist final.
__global__ void finalize_kernel(const int* __restrict__ idx3,
                                const int* __restrict__ hist,
                                float* __restrict__ out) {
    if (blockIdx.x < 64) {
        int r = blockIdx.x * 256 + threadIdx.x;
        out[OFF_MINENC + (size_t)r * N_E_G + idx3[r]] = 1.0f;
        return;
    }
    __shared__ float s[256];
    int t = threadIdx.x;
    float acc = 0.f;
    for (int k = t; k < N_E_G; k += 256) {
        float p = (float)hist[k] * (1.0f / 16384.0f);
        acc += p * logf(p + 1e-10f);
    }
    s[t] = acc;
    __syncthreads();
    for (int o = 128; o; o >>= 1) {
        if (t < o) s[t] += s[t + o];
        __syncthreads();
    }
    if (t == 0) out[OFF_PERP] = expf(-s[0]);
}

// ---------------------------------------------------------------------------
extern "C" void kernel_launch(void* const* d_in, const int* in_sizes, int n_in,
                              void* d_out, int out_size, void* d_ws, size_t ws_size,
                              hipStream_t stream) {
    const float* z_groups = (const float*)d_in[0];
    const float* emb      = (const float*)d_in[1];
    float* out = (float*)d_out;
    float* ws  = (float*)d_ws;

    float*  en   = ws + WS_EN;
    float*  en2  = ws + WS_EN2;
    ushort* ehi  = (ushort*)(ws + WS_ENHI);
    ushort* candw= (ushort*)(ws + WS_CAND);
    int*    cntw = (int*)(ws + WS_CNT);
    int*    hist = (int*)(ws + WS_HIST);
    int*    idx3 = (int*)(ws + WS_IDX3);

    norm_emb_kernel<<<1024, 256, 0, stream>>>(emb, en, en2, ehi, hist);

    cand_gen_kernel<<<dim3(NQ / 128, GROUPS), 256, 0, stream>>>(
        z_groups, ehi, out, candw, cntw);

    rescore_kernel<<<dim3(NQ / 128, GROUPS), 256, 0, stream>>>(
        z_groups, en, en2, candw, cntw, out, hist, idx3);

    finalize_kernel<<<65, 256, 0, stream>>>(idx3, hist, out);
}

// Round 10
// 407.832 us; speedup vs baseline: 1.4847x; 1.4847x over previous
//
#include <hip/hip_runtime.h>
#include <hip/hip_bf16.h>
#include <math.h>

// Problem constants
#define N_E      16384
#define E_DIM    64
#define GROUPS   4
#define N_E_G    4096
#define NQ       16384     // B*H*W query vectors

// Output layout (element offsets into d_out, float32)
#define OFF_QUANT   0L
#define OFF_VQLOSS  4194304L
#define OFF_PERP    4194316L
#define OFF_MINENC  4194317L
#define OFF_IDX     71303181L
// zero region [OFF_VQLOSS, OFF_IDX): 67,108,877 floats; aligned start.
// 512 slices x 32768 float4 cover 67,108,864; 13-float tail handled by slice 0.

// Workspace layout (element offsets into d_ws as float*/int*)
#define WS_EN     0L          // normalized emb fp32 [4][4096][64]
#define WS_EN2    1048576L    // |e|^2 per code [16384]
#define WS_ENHI   1064960L    // bf16(en) ushort [4][4096][64] -> 524288 floats
#define WS_HIST   7880704L    // int[4096]
#define WS_IDX3   7884800L    // int[16384]

typedef float  float4v  __attribute__((ext_vector_type(4)));
typedef short  short8   __attribute__((ext_vector_type(8)));

static __device__ __forceinline__ ushort f2bf(float x) {
    union { __hip_bfloat16 h; ushort u; } cv; cv.h = __float2bfloat16(x);
    return cv.u;
}

// ---------------------------------------------------------------------------
// K0: embedding normalization (1024 blocks, 4 codes/wave) + hist zeroing
// (blocks 0..15). Stream order guarantees completion before K1 starts.
__global__ void norm_emb_kernel(const float* __restrict__ emb,
                                float* __restrict__ en, float* __restrict__ en2,
                                ushort* __restrict__ ehi,
                                int* __restrict__ hist) {
    const int t    = threadIdx.x;
    const int lane = t & 63;
    const int wv   = t >> 6;

    if (blockIdx.x < 16) hist[blockIdx.x * 256 + t] = 0;

    #pragma unroll
    for (int it = 0; it < 4; ++it) {
        int code = blockIdx.x * 16 + wv * 4 + it;
        float x = emb[code * 64 + lane];
        float ss = x * x;
        #pragma unroll
        for (int off = 32; off; off >>= 1) ss += __shfl_xor(ss, off, 64);
        float v = x / fmaxf(sqrtf(ss), 1e-12f);
        en[code * 64 + lane]  = v;
        ehi[code * 64 + lane] = f2bf(v);
        float s2 = v * v;
        #pragma unroll
        for (int off = 32; off; off >>= 1) s2 += __shfl_xor(s2, off, 64);
        if (lane == 0) en2[code] = s2;
    }
}

// ---------------------------------------------------------------------------
// K1 (R10 = R2 champion + PIPELINED cross-lane threshold):
// fused z-normalize + bf16-hi MFMA candidate K-loop + in-loop NT zero-fill
// + exact fp32 rescore + NT quant/idx writes. Identical to the 388.9us R2
// champion EXCEPT the capture threshold's wave-max: champion did 2 serial
// __shfl_xor per u per tile with the result consumed immediately (~512
// exposed LDS-pipe cycles/tile in the dependent chain — the only
// latency-class ops 2-4 waves/SIMD cannot hide; R3/R6 counters show
// MfmaUtil 7.5%, VALU 17%, HBM 22% with everything else idle). R10
// pipelines the reduce across tiles: tile t issues shfl16(m_t); t+1 folds
// and issues shfl32; t+2 folds into the threshold base. Each shfl hides
// under a full tile of MFMAs. Threshold base stays a max of true acc
// values <= wave-final max and includes the current lane's m, so with
// TAU >= 2E the argmax is always captured (superset of champion's set,
// ~1-2 tiles staler -> negligible inflation; CAP 64 has ~10x headroom
// over nc~5).
// TAU >= 2*E, E = worst-case |dot - bf16hi-dot| <= 2*2^-8*(1+eps) = 7.83e-3.
#define CAP  64
#define TAU  0.017f
#define ZSTR 68            // fp32 z row stride in LDS (float4-aligned + pad)

__global__ __launch_bounds__(256, 2)
void vq_cand_kernel(const float* __restrict__ z,
                    const ushort* __restrict__ ehi,
                    const float* __restrict__ en,
                    const float* __restrict__ en2, float* __restrict__ out,
                    int* __restrict__ hist, int* __restrict__ idx3) {
    __shared__ float zn[128 * ZSTR];          // normalized fp32 z rows, 34.0 KB
    __shared__ float rden[128];
    __shared__ union {                        // tile dead before kl is born
        float tile[64 * 129];                 // 33.0 KB staging (transpose)
        struct {
            ushort cand[128 * CAP];           // 16 KB
            int    cnt[128];
            int    bks[128];
        } kl;
    } sh;                                     // total LDS ~68.4 KB -> 2 blk/CU

    const int g  = blockIdx.y;
    const int q0 = blockIdx.x * 128;
    const int t  = threadIdx.x;
    const int wave = t >> 6, lane = t & 63;
    const int l15 = lane & 15, quad = lane >> 4;
    const int qhalf = wave & 1, chalf = wave >> 1;

    const int sliceId = blockIdx.y * (NQ / 128) + blockIdx.x;   // 0..511
    float4v* fill4 = (float4v*)(out + OFF_VQLOSS) + (size_t)sliceId * 32768;

    // First codebook A-tile prefetch; completes while z-normalization runs.
    const ushort* abase = ehi + (size_t)g * N_E_G * 64
                        + (size_t)(chalf * 64 + l15) * 64 + quad * 8;
    short8 afA[4][2], afB[4][2];
    #pragma unroll
    for (int cs = 0; cs < 4; ++cs)
        #pragma unroll
        for (int ks = 0; ks < 2; ++ks)
            afA[cs][ks] = *(const short8*)(abase + (size_t)(cs * 16) * 64 + ks * 32);

    // ---- block-local z normalization (identical math to the original:
    // sequential fmaf chain, sqrtf, fmaxf(,1e-12), IEEE divide)
    {
        const int b = q0 >> 10, hw0 = q0 & 1023;
        const float* src = z + (size_t)b * 262144 + (size_t)g * 65536 + hw0;
        for (int i = t; i < 8192; i += 256) {
            int d = i >> 7, nq = i & 127;
            sh.tile[d * 129 + nq] = src[(size_t)d * 1024 + nq];
        }
        __syncthreads();
        if (t < 128) {
            float ss = 0.f;
            for (int d = 0; d < 64; ++d) {
                float x = sh.tile[d * 129 + t];
                ss = fmaf(x, x, ss);
            }
            rden[t] = fmaxf(sqrtf(ss), 1e-12f);
        }
        __syncthreads();
        for (int i = t; i < 8192; i += 256) {
            int q = i >> 6, d = i & 63;
            zn[q * ZSTR + d] = sh.tile[d * 129 + q] / rden[q];
        }
        __syncthreads();   // tile dead from here; kl region may be written
    }

    if (t < 128) sh.kl.cnt[t] = 0;

    // B-frags (queries, bf16-hi) straight from LDS, registers for the kernel
    short8 bfrag[4][2];
    #pragma unroll
    for (int uu = 0; uu < 4; ++uu) {
        int ql = qhalf * 64 + uu * 16 + l15;
        #pragma unroll
        for (int ks = 0; ks < 2; ++ks) {
            const float* p = &zn[ql * ZSTR + ks * 32 + quad * 8];
            float4v a = *(const float4v*)p;
            float4v c = *(const float4v*)(p + 4);
            short8 f;
            f[0] = (short)f2bf(a[0]); f[1] = (short)f2bf(a[1]);
            f[2] = (short)f2bf(a[2]); f[3] = (short)f2bf(a[3]);
            f[4] = (short)f2bf(c[0]); f[5] = (short)f2bf(c[1]);
            f[6] = (short)f2bf(c[2]); f[7] = (short)f2bf(c[3]);
            bfrag[uu][ks] = f;
        }
    }
    __syncthreads();   // cnt ready before first capture

    // Threshold pipeline state (per u): Mst = wave-max through tile t-2;
    // s1m/s1h = current-tile m and its in-flight shfl16; s2a/s2h = prev
    // tile's half-merged max and its in-flight shfl32.
    float Mst[4], s1m[4], s1h[4], s2a[4], s2h[4];
    #pragma unroll
    for (int u = 0; u < 4; ++u) {
        Mst[u] = -3.4e38f; s1m[u] = -3.4e38f; s1h[u] = -3.4e38f;
        s2a[u] = -3.4e38f; s2h[u] = -3.4e38f;
    }

    auto do_tile = [&](short8 (&A)[4][2], short8 (&P)[4][2], int tile) {
        if (tile + 1 < 32) {
            const ushort* p = abase + (size_t)((tile + 1) * 128) * 64;
            #pragma unroll
            for (int cs = 0; cs < 4; ++cs)
                #pragma unroll
                for (int ks = 0; ks < 2; ++ks)
                    P[cs][ks] = *(const short8*)(p + (size_t)(cs * 16) * 64 + ks * 32);
        }
        // zero-fill slice: 4 nt float4 stores per tile, after prefetch loads
        {
            const float4v z4 = {0.f, 0.f, 0.f, 0.f};
            #pragma unroll
            for (int r = 0; r < 4; ++r)
                __builtin_nontemporal_store(
                    z4, &fill4[(size_t)(tile * 4 + r) * 256 + t]);
        }
        float4v acc[4][4];
        #pragma unroll
        for (int cs = 0; cs < 4; ++cs)
            #pragma unroll
            for (int u = 0; u < 4; ++u) {
                float4v zz = {0.f, 0.f, 0.f, 0.f};
                float4v tmp = __builtin_amdgcn_mfma_f32_16x16x32_bf16(
                                  A[cs][0], bfrag[u][0], zz, 0, 0, 0);
                acc[cs][u] = __builtin_amdgcn_mfma_f32_16x16x32_bf16(
                                  A[cs][1], bfrag[u][1], tmp, 0, 0, 0);
            }
        const int j0 = tile * 128;
        #pragma unroll
        for (int u = 0; u < 4; ++u) {
            // lane-local tree max over this lane's 16 codes
            float m0 = fmaxf(fmaxf(acc[0][u][0], acc[0][u][1]),
                             fmaxf(acc[0][u][2], acc[0][u][3]));
            float m1 = fmaxf(fmaxf(acc[1][u][0], acc[1][u][1]),
                             fmaxf(acc[1][u][2], acc[1][u][3]));
            float m2 = fmaxf(fmaxf(acc[2][u][0], acc[2][u][1]),
                             fmaxf(acc[2][u][2], acc[2][u][3]));
            float m3 = fmaxf(fmaxf(acc[3][u][0], acc[3][u][1]),
                             fmaxf(acc[3][u][2], acc[3][u][3]));
            float m  = fmaxf(fmaxf(m0, m1), fmaxf(m2, m3));
            // fold stage-2 result (wave-max of m from two tiles ago);
            // s2h's shfl32 was issued last tile -> latency hidden under MFMAs
            Mst[u] = fmaxf(Mst[u], fmaxf(s2a[u], s2h[u]));
            // advance stage-1 -> stage-2 (s1h's shfl16 issued last tile)
            float a = fmaxf(s1m[u], s1h[u]);
            s2a[u] = a;
            s2h[u] = __shfl_xor(a, 32, 64);    // consumed next tile
            // start stage-1 for the current tile
            s1m[u] = m;
            s1h[u] = __shfl_xor(m, 16, 64);    // consumed next tile
            // threshold: everything cheap & already available
            float thr = fmaxf(Mst[u], fmaxf(m, a)) - TAU;
            if (m >= thr) {                    // rare
                int ql = qhalf * 64 + u * 16 + l15;
                #pragma unroll
                for (int cs = 0; cs < 4; ++cs)
                    #pragma unroll
                    for (int r = 0; r < 4; ++r)
                        if (acc[cs][u][r] >= thr) {
                            int cidx = j0 + chalf * 64 + cs * 16 + quad * 4 + r;
                            int slot = atomicAdd(&sh.kl.cnt[ql], 1);
                            if (slot < CAP) sh.kl.cand[ql * CAP + slot] = (ushort)cidx;
                        }
            }
        }
    };

    for (int tt = 0; tt < 32; tt += 2) {
        do_tile(afA, afB, tt);
        do_tile(afB, afA, tt + 1);
    }

    // 13-float tail of the zero region (unaligned remainder)
    if (sliceId == 0 && t < 13) out[OFF_VQLOSS + 67108864L + t] = 0.f;
    __syncthreads();

    // exact fp32 rescore (first-wins == min idx), z row read from LDS
    if (t < 128) {
        int q = q0 + t;
        float za[64];
        const float4v* zp = (const float4v*)(&zn[t * ZSTR]);
        #pragma unroll
        for (int i = 0; i < 16; ++i) {
            float4v v = zp[i];
            za[i*4+0] = v[0]; za[i*4+1] = v[1]; za[i*4+2] = v[2]; za[i*4+3] = v[3];
        }
        int nc = sh.kl.cnt[t]; if (nc > CAP) nc = CAP;
        float best = -3.4e38f; int bk = 0x7fffffff;
        for (int s = 0; s < nc; ++s) {
            int c = sh.kl.cand[t * CAP + s];
            const float* ev = en + ((size_t)g * N_E_G + c) * 64;
            float a = 0.f;
            #pragma unroll
            for (int k = 0; k < 64; ++k) a = fmaf(za[k], ev[k], a);
            float d = 2.f * a - en2[g * N_E_G + c];
            if (d > best || (d == best && c < bk)) { best = d; bk = c; }
        }
        if (bk == 0x7fffffff) bk = 0;
        sh.kl.bks[t] = bk;
        out[OFF_IDX + (size_t)q * 4 + g] = (float)bk;
        if (g == 3) {
            idx3[q] = bk;
            atomicAdd(&hist[bk], 1);
        }
    }
    __syncthreads();

    // quant write, coalesced along hw, non-temporal (streaming output)
    for (int i = t; i < 128 * 64; i += 256) {
        int d = i >> 7, m = i & 127;
        int n = q0 + m, b = n >> 10, hw = n & 1023;
        float v = en[((size_t)g * N_E_G + sh.kl.bks[m]) * 64 + d];
        __builtin_nontemporal_store(
            v, &out[OFF_QUANT + (size_t)b * 262144 + (size_t)(g * 64 + d) * 1024 + hw]);
    }
}

// ---------------------------------------------------------------------------
// K2: scatter ones (64 blocks, parallel) + perplexity (block 64).
// Stream-ordered after vq_cand: zero-fill complete, hist final.
__global__ void finalize_kernel(const int* __restrict__ idx3,
                                const int* __restrict__ hist,
                                float* __restrict__ out) {
    if (blockIdx.x < 64) {
        int r = blockIdx.x * 256 + threadIdx.x;
        out[OFF_MINENC + (size_t)r * N_E_G + idx3[r]] = 1.0f;
        return;
    }
    __shared__ float s[256];
    int t = threadIdx.x;
    float acc = 0.f;
    for (int k = t; k < N_E_G; k += 256) {
        float p = (float)hist[k] * (1.0f / 16384.0f);
        acc += p * logf(p + 1e-10f);
    }
    s[t] = acc;
    __syncthreads();
    for (int o = 128; o; o >>= 1) {
        if (t < o) s[t] += s[t + o];
        __syncthreads();
    }
    if (t == 0) out[OFF_PERP] = expf(-s[0]);
}

// ---------------------------------------------------------------------------
extern "C" void kernel_launch(void* const* d_in, const int* in_sizes, int n_in,
                              void* d_out, int out_size, void* d_ws, size_t ws_size,
                              hipStream_t stream) {
    const float* z_groups = (const float*)d_in[0];
    const float* emb      = (const float*)d_in[1];
    float* out = (float*)d_out;
    float* ws  = (float*)d_ws;

    float*  en   = ws + WS_EN;
    float*  en2  = ws + WS_EN2;
    ushort* ehi  = (ushort*)(ws + WS_ENHI);
    int*    hist = (int*)(ws + WS_HIST);
    int*    idx3 = (int*)(ws + WS_IDX3);

    norm_emb_kernel<<<1024, 256, 0, stream>>>(emb, en, en2, ehi, hist);

    vq_cand_kernel<<<dim3(NQ / 128, GROUPS), 256, 0, stream>>>(
        z_groups, ehi, en, en2, out, hist, idx3);

    finalize_kernel<<<65, 256, 0, stream>>>(idx3, hist, out);
}

// Round 11
// 390.061 us; speedup vs baseline: 1.5523x; 1.0456x over previous
//
#include <hip/hip_runtime.h>
#include <hip/hip_bf16.h>
#include <math.h>

// Problem constants
#define N_E      16384
#define E_DIM    64
#define GROUPS   4
#define N_E_G    4096
#define NQ       16384     // B*H*W query vectors

// Output layout (element offsets into d_out, float32)
#define OFF_QUANT   0L
#define OFF_VQLOSS  4194304L
#define OFF_PERP    4194316L
#define OFF_MINENC  4194317L
#define OFF_IDX     71303181L
// zero region [OFF_VQLOSS, OFF_IDX): 67,108,877 floats; aligned start.
// 512 slices x 32768 float4 cover 67,108,864; 13-float tail handled by slice 0.

// Workspace layout (element offsets into d_ws as float*/int*)
#define WS_EN     0L          // normalized emb fp32 [4][4096][64]
#define WS_EN2    1048576L    // |e|^2 per code [16384]
#define WS_ENHI   1064960L    // bf16(en) ushort [4][4096][64] -> 524288 floats
#define WS_HIST   7880704L    // int[4096]
#define WS_IDX3   7884800L    // int[16384]

typedef float  float4v  __attribute__((ext_vector_type(4)));
typedef short  short8   __attribute__((ext_vector_type(8)));

static __device__ __forceinline__ ushort f2bf(float x) {
    union { __hip_bfloat16 h; ushort u; } cv; cv.h = __float2bfloat16(x);
    return cv.u;
}

// ---------------------------------------------------------------------------
// K0: embedding normalization (1024 blocks, 4 codes/wave) + hist zeroing
// (blocks 0..15). Stream order guarantees completion before K1 starts.
__global__ void norm_emb_kernel(const float* __restrict__ emb,
                                float* __restrict__ en, float* __restrict__ en2,
                                ushort* __restrict__ ehi,
                                int* __restrict__ hist) {
    const int t    = threadIdx.x;
    const int lane = t & 63;
    const int wv   = t >> 6;

    if (blockIdx.x < 16) hist[blockIdx.x * 256 + t] = 0;

    #pragma unroll
    for (int it = 0; it < 4; ++it) {
        int code = blockIdx.x * 16 + wv * 4 + it;
        float x = emb[code * 64 + lane];
        float ss = x * x;
        #pragma unroll
        for (int off = 32; off; off >>= 1) ss += __shfl_xor(ss, off, 64);
        float v = x / fmaxf(sqrtf(ss), 1e-12f);
        en[code * 64 + lane]  = v;
        ehi[code * 64 + lane] = f2bf(v);
        float s2 = v * v;
        #pragma unroll
        for (int off = 32; off; off >>= 1) s2 += __shfl_xor(s2, off, 64);
        if (lane == 0) en2[code] = s2;
    }
}

// ---------------------------------------------------------------------------
// K1 (R11 = R2 champion K-loop + FAST RESCORE):
// R9's split measured rescore at ~75-100us standalone — half the kernel,
// not the K-loop (six K-loop theories each falsified R3-R10). The champion
// rescore is a 64-deep serially-dependent fmaf chain (256cy critical path
// per candidate) on 128/256 threads. R11: (a) 2 threads/query, candidates
// strided — merge by (max d, min idx), provably == serial first-wins since
// ties break by c<bk; (b) 2 interleaved candidates per thread, each chain
// keeping the EXACT k=0..63 fmaf order (per-candidate dots bit-identical);
// (c) float4 en loads (same values, rows 256B-aligned). 4 independent
// chains/query -> critical path nc*256 -> (nc/4)*256 cy.
// K-loop, z-norm, capture, fill: bit-identical to the 388.9us champion.
// TAU >= 2*E, E = worst-case |dot - bf16hi-dot| <= 2*2^-8*(1+eps) = 7.83e-3.
#define CAP  64
#define TAU  0.017f
#define ZSTR 68            // fp32 z row stride in LDS (float4-aligned + pad)

__global__ __launch_bounds__(256, 2)
void vq_cand_kernel(const float* __restrict__ z,
                    const ushort* __restrict__ ehi,
                    const float* __restrict__ en,
                    const float* __restrict__ en2, float* __restrict__ out,
                    int* __restrict__ hist, int* __restrict__ idx3) {
    __shared__ float zn[128 * ZSTR];          // normalized fp32 z rows, 34.0 KB
    __shared__ float rden[128];
    __shared__ union {                        // tile dead before kl is born
        float tile[64 * 129];                 // 33.0 KB staging (transpose)
        struct {
            ushort cand[128 * CAP];           // 16 KB
            int    cnt[128];
            int    bks[128];
            float  bestd[256];                // 2-way rescore partials
            int    bestk[256];
        } kl;                                 // 19 KB
    } sh;                                     // total LDS ~68.4 KB -> 2 blk/CU

    const int g  = blockIdx.y;
    const int q0 = blockIdx.x * 128;
    const int t  = threadIdx.x;
    const int wave = t >> 6, lane = t & 63;
    const int l15 = lane & 15, quad = lane >> 4;
    const int qhalf = wave & 1, chalf = wave >> 1;

    const int sliceId = blockIdx.y * (NQ / 128) + blockIdx.x;   // 0..511
    float4v* fill4 = (float4v*)(out + OFF_VQLOSS) + (size_t)sliceId * 32768;

    // First codebook A-tile prefetch; completes while z-normalization runs.
    const ushort* abase = ehi + (size_t)g * N_E_G * 64
                        + (size_t)(chalf * 64 + l15) * 64 + quad * 8;
    short8 afA[4][2], afB[4][2];
    #pragma unroll
    for (int cs = 0; cs < 4; ++cs)
        #pragma unroll
        for (int ks = 0; ks < 2; ++ks)
            afA[cs][ks] = *(const short8*)(abase + (size_t)(cs * 16) * 64 + ks * 32);

    // ---- block-local z normalization (identical math to the original:
    // sequential fmaf chain, sqrtf, fmaxf(,1e-12), IEEE divide)
    {
        const int b = q0 >> 10, hw0 = q0 & 1023;
        const float* src = z + (size_t)b * 262144 + (size_t)g * 65536 + hw0;
        for (int i = t; i < 8192; i += 256) {
            int d = i >> 7, nq = i & 127;
            sh.tile[d * 129 + nq] = src[(size_t)d * 1024 + nq];
        }
        __syncthreads();
        if (t < 128) {
            float ss = 0.f;
            for (int d = 0; d < 64; ++d) {
                float x = sh.tile[d * 129 + t];
                ss = fmaf(x, x, ss);
            }
            rden[t] = fmaxf(sqrtf(ss), 1e-12f);
        }
        __syncthreads();
        for (int i = t; i < 8192; i += 256) {
            int q = i >> 6, d = i & 63;
            zn[q * ZSTR + d] = sh.tile[d * 129 + q] / rden[q];
        }
        __syncthreads();   // tile dead from here; kl region may be written
    }

    if (t < 128) sh.kl.cnt[t] = 0;

    // B-frags (queries, bf16-hi) straight from LDS, registers for the kernel
    short8 bfrag[4][2];
    #pragma unroll
    for (int uu = 0; uu < 4; ++uu) {
        int ql = qhalf * 64 + uu * 16 + l15;
        #pragma unroll
        for (int ks = 0; ks < 2; ++ks) {
            const float* p = &zn[ql * ZSTR + ks * 32 + quad * 8];
            float4v a = *(const float4v*)p;
            float4v c = *(const float4v*)(p + 4);
            short8 f;
            f[0] = (short)f2bf(a[0]); f[1] = (short)f2bf(a[1]);
            f[2] = (short)f2bf(a[2]); f[3] = (short)f2bf(a[3]);
            f[4] = (short)f2bf(c[0]); f[5] = (short)f2bf(c[1]);
            f[6] = (short)f2bf(c[2]); f[7] = (short)f2bf(c[3]);
            bfrag[uu][ks] = f;
        }
    }
    __syncthreads();   // cnt ready before first capture

    float Mrun[4];
    #pragma unroll
    for (int u = 0; u < 4; ++u) Mrun[u] = -3.4e38f;

    auto do_tile = [&](short8 (&A)[4][2], short8 (&P)[4][2], int tile) {
        if (tile + 1 < 32) {
            const ushort* p = abase + (size_t)((tile + 1) * 128) * 64;
            #pragma unroll
            for (int cs = 0; cs < 4; ++cs)
                #pragma unroll
                for (int ks = 0; ks < 2; ++ks)
                    P[cs][ks] = *(const short8*)(p + (size_t)(cs * 16) * 64 + ks * 32);
        }
        // zero-fill slice: 4 nt float4 stores per tile, after prefetch loads
        {
            const float4v z4 = {0.f, 0.f, 0.f, 0.f};
            #pragma unroll
            for (int r = 0; r < 4; ++r)
                __builtin_nontemporal_store(
                    z4, &fill4[(size_t)(tile * 4 + r) * 256 + t]);
        }
        float4v acc[4][4];
        #pragma unroll
        for (int cs = 0; cs < 4; ++cs)
            #pragma unroll
            for (int u = 0; u < 4; ++u) {
                float4v zz = {0.f, 0.f, 0.f, 0.f};
                float4v tmp = __builtin_amdgcn_mfma_f32_16x16x32_bf16(
                                  A[cs][0], bfrag[u][0], zz, 0, 0, 0);
                acc[cs][u] = __builtin_amdgcn_mfma_f32_16x16x32_bf16(
                                  A[cs][1], bfrag[u][1], tmp, 0, 0, 0);
            }
        const int j0 = tile * 128;
        #pragma unroll
        for (int u = 0; u < 4; ++u) {
            float m0 = fmaxf(fmaxf(acc[0][u][0], acc[0][u][1]),
                             fmaxf(acc[0][u][2], acc[0][u][3]));
            float m1 = fmaxf(fmaxf(acc[1][u][0], acc[1][u][1]),
                             fmaxf(acc[1][u][2], acc[1][u][3]));
            float m2 = fmaxf(fmaxf(acc[2][u][0], acc[2][u][1]),
                             fmaxf(acc[2][u][2], acc[2][u][3]));
            float m3 = fmaxf(fmaxf(acc[3][u][0], acc[3][u][1]),
                             fmaxf(acc[3][u][2], acc[3][u][3]));
            float m  = fmaxf(fmaxf(m0, m1), fmaxf(m2, m3));
            float mh = fmaxf(m,  __shfl_xor(m,  16, 64));
            float mw = fmaxf(mh, __shfl_xor(mh, 32, 64));
            Mrun[u] = fmaxf(Mrun[u], mw);
            float thr = Mrun[u] - TAU;
            if (m >= thr) {                    // rare (wave-wide filter)
                int ql = qhalf * 64 + u * 16 + l15;
                #pragma unroll
                for (int cs = 0; cs < 4; ++cs)
                    #pragma unroll
                    for (int r = 0; r < 4; ++r)
                        if (acc[cs][u][r] >= thr) {
                            int cidx = j0 + chalf * 64 + cs * 16 + quad * 4 + r;
                            int slot = atomicAdd(&sh.kl.cnt[ql], 1);
                            if (slot < CAP) sh.kl.cand[ql * CAP + slot] = (ushort)cidx;
                        }
            }
        }
    };

    for (int tt = 0; tt < 32; tt += 2) {
        do_tile(afA, afB, tt);
        do_tile(afB, afA, tt + 1);
    }

    // 13-float tail of the zero region (unaligned remainder)
    if (sliceId == 0 && t < 13) out[OFF_VQLOSS + 67108864L + t] = 0.f;
    __syncthreads();

    // ---- fast exact fp32 rescore: 2 threads/query, 2 interleaved exact
    // chains per thread. Each chain preserves the serial k=0..63 fmaf order
    // (bit-identical dots); (max d, min idx) merge == serial first-wins.
    {
        int ql = t & 127, half = t >> 7;
        float za[64];
        const float4v* zp = (const float4v*)(&zn[ql * ZSTR]);
        #pragma unroll
        for (int i = 0; i < 16; ++i) {
            float4v v = zp[i];
            za[i*4+0] = v[0]; za[i*4+1] = v[1]; za[i*4+2] = v[2]; za[i*4+3] = v[3];
        }
        int nc = sh.kl.cnt[ql]; if (nc > CAP) nc = CAP;
        const ushort* cl = &sh.kl.cand[ql * CAP];
        const float*  eg = en + (size_t)g * N_E_G * 64;
        const float*  e2 = en2 + g * N_E_G;
        float best = -3.4e38f; int bk = 0x7fffffff;
        for (int s = half; s < nc; s += 4) {
            int cA = cl[s];
            int sB = s + 2;
            bool hasB = (sB < nc);
            int cB = hasB ? cl[sB] : cA;
            const float4v* eA = (const float4v*)(eg + (size_t)cA * 64);
            const float4v* eB = (const float4v*)(eg + (size_t)cB * 64);
            float aA = 0.f, aB = 0.f;
            #pragma unroll
            for (int kk = 0; kk < 16; ++kk) {
                float4v va = eA[kk], vb = eB[kk];
                aA = fmaf(za[kk*4+0], va[0], aA);
                aA = fmaf(za[kk*4+1], va[1], aA);
                aA = fmaf(za[kk*4+2], va[2], aA);
                aA = fmaf(za[kk*4+3], va[3], aA);
                aB = fmaf(za[kk*4+0], vb[0], aB);
                aB = fmaf(za[kk*4+1], vb[1], aB);
                aB = fmaf(za[kk*4+2], vb[2], aB);
                aB = fmaf(za[kk*4+3], vb[3], aB);
            }
            float dA = 2.f * aA - e2[cA];
            if (dA > best || (dA == best && cA < bk)) { best = dA; bk = cA; }
            if (hasB) {
                float dB = 2.f * aB - e2[cB];
                if (dB > best || (dB == best && cB < bk)) { best = dB; bk = cB; }
            }
        }
        sh.kl.bestd[t] = best;
        sh.kl.bestk[t] = bk;
    }
    __syncthreads();

    if (t < 128) {
        float best = sh.kl.bestd[t]; int bk = sh.kl.bestk[t];
        float d2 = sh.kl.bestd[t + 128]; int c2 = sh.kl.bestk[t + 128];
        if (d2 > best || (d2 == best && c2 < bk)) { best = d2; bk = c2; }
        if (bk == 0x7fffffff) bk = 0;
        sh.kl.bks[t] = bk;
        out[OFF_IDX + (size_t)(q0 + t) * 4 + g] = (float)bk;
        if (g == 3) {
            idx3[q0 + t] = bk;
            atomicAdd(&hist[bk], 1);
        }
    }
    __syncthreads();

    // quant write, coalesced along hw, non-temporal (streaming output)
    for (int i = t; i < 128 * 64; i += 256) {
        int d = i >> 7, m = i & 127;
        int n = q0 + m, b = n >> 10, hw = n & 1023;
        float v = en[((size_t)g * N_E_G + sh.kl.bks[m]) * 64 + d];
        __builtin_nontemporal_store(
            v, &out[OFF_QUANT + (size_t)b * 262144 + (size_t)(g * 64 + d) * 1024 + hw]);
    }
}

// ---------------------------------------------------------------------------
// K2: scatter ones (64 blocks, parallel) + perplexity (block 64).
// Stream-ordered after vq_cand: zero-fill complete, hist final.
__global__ void finalize_kernel(const int* __restrict__ idx3,
                                const int* __restrict__ hist,
                                float* __restrict__ out) {
    if (blockIdx.x < 64) {
        int r = blockIdx.x * 256 + threadIdx.x;
        out[OFF_MINENC + (size_t)r * N_E_G + idx3[r]] = 1.0f;
        return;
    }
    __shared__ float s[256];
    int t = threadIdx.x;
    float acc = 0.f;
    for (int k = t; k < N_E_G; k += 256) {
        float p = (float)hist[k] * (1.0f / 16384.0f);
        acc += p * logf(p + 1e-10f);
    }
    s[t] = acc;
    __syncthreads();
    for (int o = 128; o; o >>= 1) {
        if (t < o) s[t] += s[t + o];
        __syncthreads();
    }
    if (t == 0) out[OFF_PERP] = expf(-s[0]);
}

// ---------------------------------------------------------------------------
extern "C" void kernel_launch(void* const* d_in, const int* in_sizes, int n_in,
                              void* d_out, int out_size, void* d_ws, size_t ws_size,
                              hipStream_t stream) {
    const float* z_groups = (const float*)d_in[0];
    const float* emb      = (const float*)d_in[1];
    float* out = (float*)d_out;
    float* ws  = (float*)d_ws;

    float*  en   = ws + WS_EN;
    float*  en2  = ws + WS_EN2;
    ushort* ehi  = (ushort*)(ws + WS_ENHI);
    int*    hist = (int*)(ws + WS_HIST);
    int*    idx3 = (int*)(ws + WS_IDX3);

    norm_emb_kernel<<<1024, 256, 0, stream>>>(emb, en, en2, ehi, hist);

    vq_cand_kernel<<<dim3(NQ / 128, GROUPS), 256, 0, stream>>>(
        z_groups, ehi, en, en2, out, hist, idx3);

    finalize_kernel<<<65, 256, 0, stream>>>(idx3, hist, out);
}